// Round 8
// baseline (160.808 us; speedup 1.0000x reference)
//
#include <hip/hip_runtime.h>
#include <math.h>

#define BB 32
#define CC 2048
#define NN 784          // 28*28
#define NF4 196         // float4 per (b,c) spatial row
#define MM 4
#define NCH 64          // channel chunks for the dot pass
#define CPER (CC / NCH) // 32 channels per block
#define LAMBDA_ 1e-3f
#define EPS_ 1e-10f
#define LOG1E4 9.210340371976184f
#define NORMB (BB * CC / 4)         // 16384 rows / 4 waves
#define OUT_BLOCKS (BB * CC / 4)

__device__ __forceinline__ float wred(float v) {
#pragma unroll
  for (int off = 32; off > 0; off >>= 1) v += __shfl_down(v, off, 64);
  return v;
}

// ---- K1: wave-per-row norm -> inv_norm + pre-scaled weights Ws[b,m,c];
//          peW side-blocks (bid >= NORMB). No LDS, no barriers. ----
__global__ __launch_bounds__(256) void k_norm_w(const float* __restrict__ x,
                                                const float* __restrict__ W,
                                                float* __restrict__ inv_norm,
                                                float* __restrict__ Ws,
                                                float* __restrict__ peW) {
  int bid  = blockIdx.x;
  int wv   = threadIdx.x >> 6;
  int lane = threadIdx.x & 63;

  if (bid >= NORMB) {
    int n = bid - NORMB;
    int m = wv;
    float acc = 0.f;
    for (int c = lane; c < CC; c += 64) {
      float di  = __expf(-((float)(c & ~1) * (1.f / CC)) * LOG1E4);
      float arg = (float)n * di;
      float pe  = (c & 1) ? __cosf(arg) : __sinf(arg);
      acc += pe * W[m * CC + c];
    }
    acc = wred(acc);
    if (lane == 0) peW[m * NN + n] = acc;
    return;
  }

  int idx = bid * 4 + wv;            // (b*C+c)
  int b = idx >> 11;
  int c = idx & (CC - 1);
  const float4* row = (const float4*)(x + (size_t)idx * NN);
  float4 v0 = row[lane];
  float4 v1 = row[lane + 64];
  float4 v2 = row[lane + 128];
  float4 v3 = (lane < (NF4 - 192)) ? row[lane + 192] : make_float4(0.f, 0.f, 0.f, 0.f);
  float ss = v0.x*v0.x + v0.y*v0.y + v0.z*v0.z + v0.w*v0.w
           + v1.x*v1.x + v1.y*v1.y + v1.z*v1.z + v1.w*v1.w
           + v2.x*v2.x + v2.y*v2.y + v2.z*v2.z + v2.w*v2.w
           + v3.x*v3.x + v3.y*v3.y + v3.z*v3.z + v3.w*v3.w;
  ss = wred(ss);
  if (lane == 0) {
    float inv = 1.f / fmaxf(sqrtf(ss), EPS_);
    inv_norm[idx] = inv;
#pragma unroll
    for (int m = 0; m < MM; ++m)
      Ws[((size_t)b * MM + m) * CC + c] = W[m * CC + c] * inv;
  }
}

// ---- K2: partial dot; Ws chunk staged in LDS (one barrier, then none). ----
__global__ __launch_bounds__(256) void k_sacc4(const float* __restrict__ x,
                                               const float* __restrict__ Ws,
                                               float4* __restrict__ sPart4) {
  int t  = threadIdx.x;
  int ch = blockIdx.x;
  int b  = blockIdx.y;
  int c0 = ch * CPER;

  __shared__ float wlds[MM][CPER];
  if (t < MM * CPER) {                     // 128 threads stage 4x32 floats
    int m = t >> 5, i = t & (CPER - 1);
    wlds[m][i] = Ws[((size_t)b * MM + m) * CC + c0 + i];
  }
  __syncthreads();
  if (t >= NF4) return;

  const float4* xb = (const float4*)(x + ((size_t)b * CC + c0) * NN) + t;
  float4 a0{0,0,0,0}, a1{0,0,0,0}, a2{0,0,0,0}, a3{0,0,0,0};

  for (int i = 0; i < CPER; i += 8) {
    float4 xv[8];
#pragma unroll
    for (int u = 0; u < 8; ++u) xv[u] = xb[(size_t)(i + u) * NF4];
#pragma unroll
    for (int u = 0; u < 8; ++u) {
      float w0 = wlds[0][i + u];
      float w1 = wlds[1][i + u];
      float w2 = wlds[2][i + u];
      float w3 = wlds[3][i + u];
      float4 v = xv[u];
      a0.x += v.x * w0; a0.y += v.y * w0; a0.z += v.z * w0; a0.w += v.w * w0;
      a1.x += v.x * w1; a1.y += v.y * w1; a1.z += v.z * w1; a1.w += v.w * w1;
      a2.x += v.x * w2; a2.y += v.y * w2; a2.z += v.z * w2; a2.w += v.w * w2;
      a3.x += v.x * w3; a3.y += v.y * w3; a3.z += v.z * w3; a3.w += v.w * w3;
    }
  }
  size_t base = (((size_t)b * NCH + ch) * MM) * NF4 + t;
  sPart4[base + 0 * NF4] = a0;
  sPart4[base + 1 * NF4] = a1;
  sPart4[base + 2 * NF4] = a2;
  sPart4[base + 3 * NF4] = a3;
}

// ---- K3: hid + deterministic block-partial aD = sum_n hid^2 ----
__global__ __launch_bounds__(256) void k_hid2(const float* __restrict__ sPart,
                                              const float* __restrict__ peW,
                                              float* __restrict__ hid4,
                                              float* __restrict__ aDpart) {
  int g = blockIdx.x;            // n-chunk 0..3
  int b = blockIdx.y;
  int t = threadIdx.x;
  int n = g * 256 + t;
  bool valid = n < NN;
  int wv = t >> 6, lane = t & 63;

  float h[MM];
#pragma unroll
  for (int m = 0; m < MM; ++m) {
    float hm = 0.f;
    if (valid) {
      float s = peW[m * NN + n];
#pragma unroll 8
      for (int ch = 0; ch < NCH; ++ch)
        s += sPart[(((size_t)b * NCH + ch) * MM + m) * NN + n];
      hm = 1.f / (1.f + __expf(-s));
    }
    h[m] = hm;
  }
  if (valid) {
    float4 hv = make_float4(h[0], h[1], h[2], h[3]);
    *(float4*)(hid4 + ((size_t)b * NN + n) * 4) = hv;
  }

  __shared__ float red[4][MM];
#pragma unroll
  for (int m = 0; m < MM; ++m) {
    float q = wred(h[m] * h[m]);
    if (lane == 0) red[wv][m] = q;
  }
  __syncthreads();
  if (t < MM)
    aDpart[((size_t)b * 4 + g) * MM + t] = red[0][t] + red[1][t] + red[2][t] + red[3][t];
}

// ---- K4: out[b,c] = sum_m (inv*aX[m] + aP[m]) / (aD[m]+lambda);
//          pe via angle-addition rotation (3 sincos total per lane). ----
__global__ __launch_bounds__(256) void k_out2(const float* __restrict__ x,
                                              const float* __restrict__ hid4,
                                              const float* __restrict__ inv_norm,
                                              const float* __restrict__ aDpart,
                                              float* __restrict__ out) {
  int idx  = blockIdx.x * 4 + (threadIdx.x >> 6);   // (b*C+c)
  int lane = threadIdx.x & 63;
  int b = idx >> 11;
  int c = idx & (CC - 1);
  const float4* row = (const float4*)(x + (size_t)idx * NN);
  const float4* hb  = (const float4*)(hid4 + (size_t)b * NN * 4);
  float di = __expf(-((float)(c & ~1) * (1.0f / CC)) * LOG1E4);
  bool use_sin = !(c & 1);

  // trig state: (s,cO) = sincos(n0*di), n0 = 4*lane; quad offsets 1..3; step 256.
  float s, cO;  __sincosf((float)(4 * lane) * di, &s, &cO);
  float s1, c1; __sincosf(di, &s1, &c1);
  float s2 = 2.f * s1 * c1, c2 = 1.f - 2.f * s1 * s1;
  float s3 = s1 * c2 + c1 * s2, c3 = c1 * c2 - s1 * s2;
  float SD, CD; __sincosf(256.f * di, &SD, &CD);

  float aX0=0,aX1=0,aX2=0,aX3=0, aP0=0,aP1=0,aP2=0,aP3=0;
  for (int f = lane; f < NF4; f += 64) {
    float4 xv = row[f];
    int n = f * 4;
    float4 h0 = hb[n + 0], h1 = hb[n + 1], h2 = hb[n + 2], h3 = hb[n + 3];
    float p0, p1, p2, p3;
    if (use_sin) {
      p0 = s;
      p1 = s * c1 + cO * s1;
      p2 = s * c2 + cO * s2;
      p3 = s * c3 + cO * s3;
    } else {
      p0 = cO;
      p1 = cO * c1 - s * s1;
      p2 = cO * c2 - s * s2;
      p3 = cO * c3 - s * s3;
    }
    aX0 += xv.x*h0.x + xv.y*h1.x + xv.z*h2.x + xv.w*h3.x;
    aX1 += xv.x*h0.y + xv.y*h1.y + xv.z*h2.y + xv.w*h3.y;
    aX2 += xv.x*h0.z + xv.y*h1.z + xv.z*h2.z + xv.w*h3.z;
    aX3 += xv.x*h0.w + xv.y*h1.w + xv.z*h2.w + xv.w*h3.w;
    aP0 += p0*h0.x + p1*h1.x + p2*h2.x + p3*h3.x;
    aP1 += p0*h0.y + p1*h1.y + p2*h2.y + p3*h3.y;
    aP2 += p0*h0.z + p1*h1.z + p2*h2.z + p3*h3.z;
    aP3 += p0*h0.w + p1*h1.w + p2*h2.w + p3*h3.w;
    float ns = s * CD + cO * SD;
    float nc = cO * CD - s * SD;
    s = ns; cO = nc;
  }
  aX0 = wred(aX0); aX1 = wred(aX1); aX2 = wred(aX2); aX3 = wred(aX3);
  aP0 = wred(aP0); aP1 = wred(aP1); aP2 = wred(aP2); aP3 = wred(aP3);
  if (lane == 0) {
    const float* ad = aDpart + (size_t)b * 4 * MM;
    float aD0 = ad[0] + ad[4] + ad[8]  + ad[12];
    float aD1 = ad[1] + ad[5] + ad[9]  + ad[13];
    float aD2 = ad[2] + ad[6] + ad[10] + ad[14];
    float aD3 = ad[3] + ad[7] + ad[11] + ad[15];
    float inv = inv_norm[idx];
    float r = (inv * aX0 + aP0) / (aD0 + LAMBDA_)
            + (inv * aX1 + aP1) / (aD1 + LAMBDA_)
            + (inv * aX2 + aP2) / (aD2 + LAMBDA_)
            + (inv * aX3 + aP3) / (aD3 + LAMBDA_);
    if (isnan(r)) r = 0.f;
    else if (isinf(r)) r = (r > 0.f) ? 3.4028234663852886e38f : -3.4028234663852886e38f;
    out[idx] = r;
  }
}

extern "C" void kernel_launch(void* const* d_in, const int* in_sizes, int n_in,
                              void* d_out, int out_size, void* d_ws, size_t ws_size,
                              hipStream_t stream) {
  const float* x = (const float*)d_in[0];   // (B, C, S, S)
  const float* W = (const float*)d_in[1];   // (M, C, 1)
  float* out = (float*)d_out;               // (B, 1, C)
  float* ws  = (float*)d_ws;

  float* inv_norm = ws;                                   // B*C        = 65536
  float* peW      = inv_norm + (size_t)BB * CC;           // M*N        = 3136
  float* hid4     = peW + (size_t)MM * NN;                // B*N*M      = 401408
  float* Ws       = hid4 + (size_t)BB * NN * MM;          // B*M*C      = 262144
  float* aDpart   = Ws + (size_t)BB * MM * CC;            // B*4*M      = 512
  float* sPart    = aDpart + (size_t)BB * 4 * MM;         // B*NCH*M*N  = 6.4M floats

  k_norm_w<<<NORMB + NN, 256, 0, stream>>>(x, W, inv_norm, Ws, peW);
  k_sacc4<<<dim3(NCH, BB), 256, 0, stream>>>(x, Ws, (float4*)sPart);
  k_hid2<<<dim3(4, BB), 256, 0, stream>>>(sPart, peW, hid4, aDpart);
  k_out2<<<OUT_BLOCKS, 256, 0, stream>>>(x, hid4, inv_norm, aDpart, out);
}